// Round 1
// baseline (6528.907 us; speedup 1.0000x reference)
//
#include <hip/hip_runtime.h>
#include <stdint.h>

typedef __attribute__((ext_vector_type(8))) short short8;
typedef __attribute__((ext_vector_type(4))) float f32x4;
typedef __attribute__((ext_vector_type(4))) unsigned short ushort4v;
typedef __attribute__((ext_vector_type(4))) float float4v;

#define DEVFN static __device__ __forceinline__

DEVFN unsigned short f32_to_bf16_rn(float x) {
  unsigned u = __builtin_bit_cast(unsigned, x);
  unsigned r = u + 0x7FFFu + ((u >> 16) & 1u);
  return (unsigned short)(r >> 16);
}
DEVFN float bf16_to_f32(unsigned short h) {
  unsigned u = ((unsigned)h) << 16;
  return __builtin_bit_cast(float, u);
}

// ---------------- split f32 -> (hi,lo) bf16 ----------------
__global__ void k_split(const float* __restrict__ src, unsigned short* __restrict__ hi,
                        unsigned short* __restrict__ lo, int n) {
  int i = (blockIdx.x * 256 + threadIdx.x) * 4;
  if (i >= n) return;
  float4v v = *reinterpret_cast<const float4v*>(src + i);
  ushort4v h, l;
#pragma unroll
  for (int j = 0; j < 4; ++j) {
    unsigned short hb = f32_to_bf16_rn(v[j]);
    float rem = v[j] - bf16_to_f32(hb);
    h[j] = hb;
    l[j] = f32_to_bf16_rn(rem);
  }
  *reinterpret_cast<ushort4v*>(hi + i) = h;
  *reinterpret_cast<ushort4v*>(lo + i) = l;
}

// ---------------- embedding gather + split ----------------
__global__ void k_embed(const int* __restrict__ tok, const float* __restrict__ emb,
                        unsigned short* __restrict__ hi, unsigned short* __restrict__ lo) {
  int m = blockIdx.x;                       // 0..8191  (s*64+b)
  int t = tok[m];
  const float* row = emb + (size_t)t * 1024;
  int e = threadIdx.x * 4;
  float4v v = *reinterpret_cast<const float4v*>(row + e);
  ushort4v h, l;
#pragma unroll
  for (int j = 0; j < 4; ++j) {
    unsigned short hb = f32_to_bf16_rn(v[j]);
    float rem = v[j] - bf16_to_f32(hb);
    h[j] = hb;
    l[j] = f32_to_bf16_rn(rem);
  }
  *reinterpret_cast<ushort4v*>(hi + (size_t)m * 1024 + e) = h;
  *reinterpret_cast<ushort4v*>(lo + (size_t)m * 1024 + e) = l;
}

// ---------------- NT GEMM, 3-term bf16 split, C = A@B.T + bias ----------------
// A: [M][K] (hi/lo bf16), B: [N][K] (hi/lo bf16), C: [M][N] f32. K == 1024.
template <bool NGUARD>
__global__ __launch_bounds__(256) void k_gemm_nt(
    const unsigned short* __restrict__ Ahi, const unsigned short* __restrict__ Alo,
    const unsigned short* __restrict__ Bhi, const unsigned short* __restrict__ Blo,
    float* __restrict__ C, const float* __restrict__ bias, int N) {
  const int K = 1024;
  __shared__ unsigned short sA[2][128][40];  // +8 pad: 2-way banks only
  __shared__ unsigned short sB[2][128][40];
  const int m0 = blockIdx.y * 128;
  const int n0 = blockIdx.x * 128;
  const int tid = threadIdx.x;
  const int lane = tid & 63, wave = tid >> 6;
  const int wm = (wave >> 1) * 64, wn = (wave & 1) * 64;
  const int fr = lane & 15, fk = (lane >> 4) * 8, fm = (lane >> 4) * 4;

  f32x4 acc[4][4] = {};

  for (int k0 = 0; k0 < K; k0 += 32) {
    __syncthreads();
#pragma unroll
    for (int a = 0; a < 2; ++a) {
      const unsigned short* As = a ? Alo : Ahi;
      const unsigned short* Bs = a ? Blo : Bhi;
#pragma unroll
      for (int p = 0; p < 2; ++p) {
        int seg = p * 256 + tid;              // 0..511
        int row = seg >> 2, sk = (seg & 3) * 8;
        short8 va = *reinterpret_cast<const short8*>(As + (size_t)(m0 + row) * K + k0 + sk);
        *reinterpret_cast<short8*>(&sA[a][row][sk]) = va;
        short8 vb;
        if (!NGUARD || (n0 + row) < N)
          vb = *reinterpret_cast<const short8*>(Bs + (size_t)(n0 + row) * K + k0 + sk);
        else
          vb = short8{0, 0, 0, 0, 0, 0, 0, 0};
        *reinterpret_cast<short8*>(&sB[a][row][sk]) = vb;
      }
    }
    __syncthreads();

    short8 afh[4], afl[4], bfh[4], bfl[4];
#pragma unroll
    for (int i = 0; i < 4; ++i) {
      afh[i] = *reinterpret_cast<const short8*>(&sA[0][wm + i * 16 + fr][fk]);
      afl[i] = *reinterpret_cast<const short8*>(&sA[1][wm + i * 16 + fr][fk]);
      bfh[i] = *reinterpret_cast<const short8*>(&sB[0][wn + i * 16 + fr][fk]);
      bfl[i] = *reinterpret_cast<const short8*>(&sB[1][wn + i * 16 + fr][fk]);
    }
#pragma unroll
    for (int i = 0; i < 4; ++i)
#pragma unroll
      for (int j = 0; j < 4; ++j) {
        acc[i][j] = __builtin_amdgcn_mfma_f32_16x16x32_bf16(afh[i], bfh[j], acc[i][j], 0, 0, 0);
        acc[i][j] = __builtin_amdgcn_mfma_f32_16x16x32_bf16(afl[i], bfh[j], acc[i][j], 0, 0, 0);
        acc[i][j] = __builtin_amdgcn_mfma_f32_16x16x32_bf16(afh[i], bfl[j], acc[i][j], 0, 0, 0);
      }
  }

#pragma unroll
  for (int i = 0; i < 4; ++i)
#pragma unroll
    for (int j = 0; j < 4; ++j) {
      int n = n0 + wn + j * 16 + fr;
      if (NGUARD && n >= N) continue;
      float bv = bias[n];
#pragma unroll
      for (int r = 0; r < 4; ++r) {
        int m = m0 + wm + i * 16 + fm + r;
        C[(size_t)m * N + n] = acc[i][j][r] + bv;
      }
    }
}

// ---------------- software grid barrier ----------------
DEVFN void gbar(unsigned* cnt, unsigned target) {
  __syncthreads();
  if (threadIdx.x == 0) {
    __hip_atomic_fetch_add(cnt, 1u, __ATOMIC_RELEASE, __HIP_MEMORY_SCOPE_AGENT);
    while (__hip_atomic_load(cnt, __ATOMIC_RELAXED, __HIP_MEMORY_SCOPE_AGENT) < target)
      __builtin_amdgcn_s_sleep(2);
    __threadfence();  // acquire: invalidate stale cached h
  }
  __syncthreads();
}

// ---------------- persistent recurrence kernel (one layer) ----------------
// X: [128][64][1024] f32 (pre-added input transform + bias)
// Hseq hi/lo: [129][64][1024] bf16; slot 0 pre-filled with split(h_init)
// W hi/lo: [1024][1024] bf16 (wh). Grid: 64 WGs x 256 thr, WG j owns cols 16j..16j+15.
__global__ __launch_bounds__(256) void k_rnn(
    const float* __restrict__ X, unsigned short* __restrict__ Hhi,
    unsigned short* __restrict__ Hlo, const unsigned short* __restrict__ Whi,
    const unsigned short* __restrict__ Wlo, unsigned* __restrict__ cnt) {
  const int tid = threadIdx.x;
  const int lane = tid & 63, wave = tid >> 6;
  const int m0 = wave * 16;             // batch rows for this wave
  const int n0 = blockIdx.x * 16;       // output cols for this WG
  const int fr = lane & 15, fk = (lane >> 4) * 8, fm = (lane >> 4) * 4;
  const unsigned short* wh = Whi + (size_t)(n0 + fr) * 1024 + fk;
  const unsigned short* wl = Wlo + (size_t)(n0 + fr) * 1024 + fk;

  for (int t = 0; t < 128; ++t) {
    const unsigned short* ah = Hhi + (size_t)t * 65536 + (size_t)(m0 + fr) * 1024 + fk;
    const unsigned short* al = Hlo + (size_t)t * 65536 + (size_t)(m0 + fr) * 1024 + fk;
    f32x4 acc00 = {}, acc01 = {}, acc02 = {}, acc10 = {}, acc11 = {}, acc12 = {};
#pragma unroll 4
    for (int kc = 0; kc < 1024; kc += 64) {
      short8 a_h0 = *reinterpret_cast<const short8*>(ah + kc);
      short8 a_l0 = *reinterpret_cast<const short8*>(al + kc);
      short8 b_h0 = *reinterpret_cast<const short8*>(wh + kc);
      short8 b_l0 = *reinterpret_cast<const short8*>(wl + kc);
      short8 a_h1 = *reinterpret_cast<const short8*>(ah + kc + 32);
      short8 a_l1 = *reinterpret_cast<const short8*>(al + kc + 32);
      short8 b_h1 = *reinterpret_cast<const short8*>(wh + kc + 32);
      short8 b_l1 = *reinterpret_cast<const short8*>(wl + kc + 32);
      acc00 = __builtin_amdgcn_mfma_f32_16x16x32_bf16(a_h0, b_h0, acc00, 0, 0, 0);
      acc01 = __builtin_amdgcn_mfma_f32_16x16x32_bf16(a_l0, b_h0, acc01, 0, 0, 0);
      acc02 = __builtin_amdgcn_mfma_f32_16x16x32_bf16(a_h0, b_l0, acc02, 0, 0, 0);
      acc10 = __builtin_amdgcn_mfma_f32_16x16x32_bf16(a_h1, b_h1, acc10, 0, 0, 0);
      acc11 = __builtin_amdgcn_mfma_f32_16x16x32_bf16(a_l1, b_h1, acc11, 0, 0, 0);
      acc12 = __builtin_amdgcn_mfma_f32_16x16x32_bf16(a_h1, b_l1, acc12, 0, 0, 0);
    }
    f32x4 s = ((acc00 + acc10) + (acc01 + acc11)) + (acc02 + acc12);

    const float* Xt = X + (size_t)t * 65536;
    unsigned short* oh = Hhi + (size_t)(t + 1) * 65536;
    unsigned short* ol = Hlo + (size_t)(t + 1) * 65536;
#pragma unroll
    for (int r = 0; r < 4; ++r) {
      int m = m0 + fm + r;
      int n = n0 + fr;
      float val = tanhf(Xt[(size_t)m * 1024 + n] + s[r]);
      unsigned short hb = f32_to_bf16_rn(val);
      float rem = val - bf16_to_f32(hb);
      oh[(size_t)m * 1024 + n] = hb;
      ol[(size_t)m * 1024 + n] = f32_to_bf16_rn(rem);
    }
    gbar(cnt, 64u * (t + 1));
  }
}

// ---------------- final hidden state: reconstruct f32 = hi + lo ----------------
__global__ void k_hidfinal(const unsigned short* __restrict__ H0hi,
                           const unsigned short* __restrict__ H0lo,
                           const unsigned short* __restrict__ H1hi,
                           const unsigned short* __restrict__ H1lo,
                           float* __restrict__ out) {
  size_t i = (size_t)blockIdx.x * 256 + threadIdx.x;  // 0..65535
  const size_t off = (size_t)128 * 65536;
  out[i] = bf16_to_f32(H0hi[off + i]) + bf16_to_f32(H0lo[off + i]);
  out[65536 + i] = bf16_to_f32(H1hi[off + i]) + bf16_to_f32(H1lo[off + i]);
}

// ---------------- launch ----------------
extern "C" void kernel_launch(void* const* d_in, const int* in_sizes, int n_in,
                              void* d_out, int out_size, void* d_ws, size_t ws_size,
                              hipStream_t stream) {
  const int* inputs = (const int*)d_in[0];     // (128,64) int32
  const float* hidden = (const float*)d_in[1]; // (2,64,1024)
  const float* emb = (const float*)d_in[2];    // (10000,1024)
  const float* wx0 = (const float*)d_in[3];
  const float* wh0 = (const float*)d_in[4];
  const float* bh0 = (const float*)d_in[5];
  const float* wx1 = (const float*)d_in[6];
  const float* wh1 = (const float*)d_in[7];
  const float* bh1 = (const float*)d_in[8];
  const float* v_w = (const float*)d_in[9];    // (10000,1024)
  const float* v_b = (const float*)d_in[10];   // (10000,)
  float* out = (float*)d_out;                  // logits 81,920,000 + hidden 131,072

  char* ws = (char*)d_ws;
  size_t off = 0;
  auto alloc = [&](size_t bytes) -> char* {
    char* p = ws + off;
    off += (bytes + 255) & ~(size_t)255;
    return p;
  };
  const size_t WB = (size_t)1024 * 1024 * 2;        // one split copy of a 1024^2 matrix
  unsigned short* wx0hi = (unsigned short*)alloc(WB);
  unsigned short* wx0lo = (unsigned short*)alloc(WB);
  unsigned short* wh0hi = (unsigned short*)alloc(WB);
  unsigned short* wh0lo = (unsigned short*)alloc(WB);
  unsigned short* wx1hi = (unsigned short*)alloc(WB);
  unsigned short* wx1lo = (unsigned short*)alloc(WB);
  unsigned short* wh1hi = (unsigned short*)alloc(WB);
  unsigned short* wh1lo = (unsigned short*)alloc(WB);
  unsigned short* vwhi = (unsigned short*)alloc((size_t)10000 * 1024 * 2);
  unsigned short* vwlo = (unsigned short*)alloc((size_t)10000 * 1024 * 2);
  unsigned short* aehi = (unsigned short*)alloc((size_t)8192 * 1024 * 2);
  unsigned short* aelo = (unsigned short*)alloc((size_t)8192 * 1024 * 2);
  float* X0 = (float*)alloc((size_t)8192 * 1024 * 4);
  float* X1 = (float*)alloc((size_t)8192 * 1024 * 4);
  const size_t HS = (size_t)129 * 65536 * 2;        // 129 slots
  unsigned short* H0hi = (unsigned short*)alloc(HS);
  unsigned short* H0lo = (unsigned short*)alloc(HS);
  unsigned short* H1hi = (unsigned short*)alloc(HS);
  unsigned short* H1lo = (unsigned short*)alloc(HS);
  unsigned* cnt = (unsigned*)alloc(256);
  unsigned* cnt0 = cnt;
  unsigned* cnt1 = cnt + 16;

  // weight / state splits
  k_split<<<1024, 256, 0, stream>>>(wx0, wx0hi, wx0lo, 1024 * 1024);
  k_split<<<1024, 256, 0, stream>>>(wh0, wh0hi, wh0lo, 1024 * 1024);
  k_split<<<1024, 256, 0, stream>>>(wx1, wx1hi, wx1lo, 1024 * 1024);
  k_split<<<1024, 256, 0, stream>>>(wh1, wh1hi, wh1lo, 1024 * 1024);
  k_split<<<10000, 256, 0, stream>>>(v_w, vwhi, vwlo, 10000 * 1024);
  k_split<<<64, 256, 0, stream>>>(hidden, H0hi, H0lo, 65536);          // slot 0, layer 0
  k_split<<<64, 256, 0, stream>>>(hidden + 65536, H1hi, H1lo, 65536);  // slot 0, layer 1
  k_embed<<<8192, 256, 0, stream>>>(inputs, emb, aehi, aelo);
  hipMemsetAsync(cnt, 0, 256, stream);

  dim3 g1(8, 64);   // N=1024 -> 8 tiles, M=8192 -> 64 tiles
  k_gemm_nt<false><<<g1, 256, 0, stream>>>(aehi, aelo, wx0hi, wx0lo, X0, bh0, 1024);
  k_rnn<<<64, 256, 0, stream>>>(X0, H0hi, H0lo, wh0hi, wh0lo, cnt0);
  k_gemm_nt<false><<<g1, 256, 0, stream>>>(H0hi + 65536, H0lo + 65536, wx1hi, wx1lo, X1, bh1, 1024);
  k_rnn<<<64, 256, 0, stream>>>(X1, H1hi, H1lo, wh1hi, wh1lo, cnt1);
  dim3 g3(79, 64);  // N=10000 -> 79 tiles (guarded)
  k_gemm_nt<true><<<g3, 256, 0, stream>>>(H1hi + 65536, H1lo + 65536, vwhi, vwlo, out, v_b, 10000);
  k_hidfinal<<<256, 256, 0, stream>>>(H0hi, H0lo, H1hi, H1lo, out + (size_t)81920000);
}

// Round 5
// 3704.147 us; speedup vs baseline: 1.7626x; 1.7626x over previous
//
#include <hip/hip_runtime.h>
#include <stdint.h>

typedef __attribute__((ext_vector_type(8))) short short8;
typedef __attribute__((ext_vector_type(4))) float f32x4;
typedef __attribute__((ext_vector_type(4))) unsigned short ushort4v;
typedef __attribute__((ext_vector_type(4))) float float4v;

#define DEVFN static __device__ __forceinline__
#define SPIN_CAP (1u << 20)  // failsafe: wrong-results > wedged-container

DEVFN unsigned short f32_to_bf16_rn(float x) {
  unsigned u = __builtin_bit_cast(unsigned, x);
  unsigned r = u + 0x7FFFu + ((u >> 16) & 1u);
  return (unsigned short)(r >> 16);
}
DEVFN float bf16_to_f32(unsigned short h) {
  unsigned u = ((unsigned)h) << 16;
  return __builtin_bit_cast(float, u);
}

// ---------------- split f32 -> (hi,lo) bf16 ----------------
__global__ void k_split(const float* __restrict__ src, unsigned short* __restrict__ hi,
                        unsigned short* __restrict__ lo, int n) {
  int i = (blockIdx.x * 256 + threadIdx.x) * 4;
  if (i >= n) return;
  float4v v = *reinterpret_cast<const float4v*>(src + i);
  ushort4v h, l;
#pragma unroll
  for (int j = 0; j < 4; ++j) {
    unsigned short hb = f32_to_bf16_rn(v[j]);
    float rem = v[j] - bf16_to_f32(hb);
    h[j] = hb;
    l[j] = f32_to_bf16_rn(rem);
  }
  *reinterpret_cast<ushort4v*>(hi + i) = h;
  *reinterpret_cast<ushort4v*>(lo + i) = l;
}

// ---------------- embedding gather + split ----------------
__global__ void k_embed(const int* __restrict__ tok, const float* __restrict__ emb,
                        unsigned short* __restrict__ hi, unsigned short* __restrict__ lo) {
  int m = blockIdx.x;  // 0..8191  (s*64+b)
  int t = tok[m];
  const float* row = emb + (size_t)t * 1024;
  int e = threadIdx.x * 4;
  float4v v = *reinterpret_cast<const float4v*>(row + e);
  ushort4v h, l;
#pragma unroll
  for (int j = 0; j < 4; ++j) {
    unsigned short hb = f32_to_bf16_rn(v[j]);
    float rem = v[j] - bf16_to_f32(hb);
    h[j] = hb;
    l[j] = f32_to_bf16_rn(rem);
  }
  *reinterpret_cast<ushort4v*>(hi + (size_t)m * 1024 + e) = h;
  *reinterpret_cast<ushort4v*>(lo + (size_t)m * 1024 + e) = l;
}

// ---------------- NT GEMM, 3-term bf16 split, C = A@B.T + bias ----------------
template <bool NGUARD>
__global__ __launch_bounds__(256) void k_gemm_nt(
    const unsigned short* __restrict__ Ahi, const unsigned short* __restrict__ Alo,
    const unsigned short* __restrict__ Bhi, const unsigned short* __restrict__ Blo,
    float* __restrict__ C, const float* __restrict__ bias, int N) {
  const int K = 1024;
  __shared__ unsigned short sA[2][128][40];
  __shared__ unsigned short sB[2][128][40];
  const int m0 = blockIdx.y * 128;
  const int n0 = blockIdx.x * 128;
  const int tid = threadIdx.x;
  const int lane = tid & 63, wave = tid >> 6;
  const int wm = (wave >> 1) * 64, wn = (wave & 1) * 64;
  const int fr = lane & 15, fk = (lane >> 4) * 8, fm = (lane >> 4) * 4;

  f32x4 acc[4][4] = {};

  for (int k0 = 0; k0 < K; k0 += 32) {
    __syncthreads();
#pragma unroll
    for (int a = 0; a < 2; ++a) {
      const unsigned short* As = a ? Alo : Ahi;
      const unsigned short* Bs = a ? Blo : Bhi;
#pragma unroll
      for (int p = 0; p < 2; ++p) {
        int seg = p * 256 + tid;
        int row = seg >> 2, sk = (seg & 3) * 8;
        short8 va = *reinterpret_cast<const short8*>(As + (size_t)(m0 + row) * K + k0 + sk);
        *reinterpret_cast<short8*>(&sA[a][row][sk]) = va;
        short8 vb;
        if (!NGUARD || (n0 + row) < N)
          vb = *reinterpret_cast<const short8*>(Bs + (size_t)(n0 + row) * K + k0 + sk);
        else
          vb = short8{0, 0, 0, 0, 0, 0, 0, 0};
        *reinterpret_cast<short8*>(&sB[a][row][sk]) = vb;
      }
    }
    __syncthreads();

    short8 afh[4], afl[4], bfh[4], bfl[4];
#pragma unroll
    for (int i = 0; i < 4; ++i) {
      afh[i] = *reinterpret_cast<const short8*>(&sA[0][wm + i * 16 + fr][fk]);
      afl[i] = *reinterpret_cast<const short8*>(&sA[1][wm + i * 16 + fr][fk]);
      bfh[i] = *reinterpret_cast<const short8*>(&sB[0][wn + i * 16 + fr][fk]);
      bfl[i] = *reinterpret_cast<const short8*>(&sB[1][wn + i * 16 + fr][fk]);
    }
#pragma unroll
    for (int i = 0; i < 4; ++i)
#pragma unroll
      for (int j = 0; j < 4; ++j) {
        acc[i][j] = __builtin_amdgcn_mfma_f32_16x16x32_bf16(afh[i], bfh[j], acc[i][j], 0, 0, 0);
        acc[i][j] = __builtin_amdgcn_mfma_f32_16x16x32_bf16(afl[i], bfh[j], acc[i][j], 0, 0, 0);
        acc[i][j] = __builtin_amdgcn_mfma_f32_16x16x32_bf16(afh[i], bfl[j], acc[i][j], 0, 0, 0);
      }
  }

#pragma unroll
  for (int i = 0; i < 4; ++i)
#pragma unroll
    for (int j = 0; j < 4; ++j) {
      int n = n0 + wn + j * 16 + fr;
      if (NGUARD && n >= N) continue;
      float bv = bias[n];
#pragma unroll
      for (int r = 0; r < 4; ++r) {
        int m = m0 + wm + i * 16 + fm + r;
        C[(size_t)m * N + n] = acc[i][j][r] + bv;
      }
    }
}

// ---------------- fused 2-layer recurrence, persistent ----------------
// Grid: 97 WGs x 256. WG 0..31: layer-0 (32 cols each). WG 32..95: layer-1
// (16 cols each, wx1+wh1 both folded). WG 96: barrier checker.
// Interval i (0..128): L0 computes h0[i+1] (i<128); L1 computes h1[i] (i>=1).
// W held in registers (4-wave k-split, k=256/wave); cross-wave LDS reduce.
// Barrier: per-WG slot store + checker wave polls all slots + release flag.
// All spin loops are BOUNDED (SPIN_CAP): a sync bug produces wrong data +
// counters instead of a wedged container.
#define NWG_L0 32
#define NWG_CMP 96

DEVFN f32x4 MFMA(short8 a, short8 b, f32x4 c) {
  return __builtin_amdgcn_mfma_f32_16x16x32_bf16(a, b, c, 0, 0, 0);
}

__global__ __launch_bounds__(256, 1) void k_rnn_fused(
    const float* __restrict__ X0,
    unsigned short* __restrict__ H0hi, unsigned short* __restrict__ H0lo,
    unsigned short* __restrict__ H1hi, unsigned short* __restrict__ H1lo,
    const unsigned short* __restrict__ Wh0hi, const unsigned short* __restrict__ Wh0lo,
    const unsigned short* __restrict__ Wx1hi, const unsigned short* __restrict__ Wx1lo,
    const unsigned short* __restrict__ Wh1hi, const unsigned short* __restrict__ Wh1lo,
    const float* __restrict__ bh1,
    unsigned* __restrict__ slots, unsigned* __restrict__ release) {
  const int wg = blockIdx.x;
  const int tid = threadIdx.x;

  if (wg == NWG_CMP) {  // ---- checker: wave 0 polls all 96 slots ----
    if (tid >= 64) return;
    const int lane = tid;
    for (int i = 0; i < 129; ++i) {
      unsigned want = (unsigned)(i + 1);
      for (unsigned sp = 0; sp < SPIN_CAP; ++sp) {
        unsigned a = __hip_atomic_load(&slots[lane * 32], __ATOMIC_RELAXED,
                                       __HIP_MEMORY_SCOPE_AGENT);
        unsigned b = (lane < 32) ? __hip_atomic_load(&slots[(64 + lane) * 32], __ATOMIC_RELAXED,
                                                     __HIP_MEMORY_SCOPE_AGENT)
                                 : 0xFFFFFFFFu;
        if (__all(a >= want && b >= want)) break;
        __builtin_amdgcn_s_sleep(1);
      }
      if (lane == 0)
        __hip_atomic_store(release, want, __ATOMIC_RELAXED, __HIP_MEMORY_SCOPE_AGENT);
    }
    return;
  }

  const int lane = tid & 63, kw = tid >> 6;  // kw: wave = k-slice owner
  const int fr = lane & 15, fk = (lane >> 4) * 8;
  const int pr = (lane >> 4) * 4;
  const bool isL0 = wg < NWG_L0;
  __shared__ float red[4][64][36];

  // ---- preload weight fragments into registers (held across all steps) ----
  short8 bh_[2][8], bl_[2][8];
  int n0;
  if (isL0) {
    n0 = wg * 32;
#pragma unroll
    for (int cf = 0; cf < 2; ++cf)
#pragma unroll
      for (int ch = 0; ch < 8; ++ch) {
        size_t off = (size_t)(n0 + cf * 16 + fr) * 1024 + kw * 256 + ch * 32 + fk;
        bh_[cf][ch] = *reinterpret_cast<const short8*>(Wh0hi + off);
        bl_[cf][ch] = *reinterpret_cast<const short8*>(Wh0lo + off);
      }
  } else {
    n0 = (wg - NWG_L0) * 16;
#pragma unroll
    for (int ch = 0; ch < 8; ++ch) {
      size_t off = (size_t)(n0 + fr) * 1024 + kw * 256 + ch * 32 + fk;
      bh_[0][ch] = *reinterpret_cast<const short8*>(Wx1hi + off);
      bl_[0][ch] = *reinterpret_cast<const short8*>(Wx1lo + off);
      bh_[1][ch] = *reinterpret_cast<const short8*>(Wh1hi + off);
      bl_[1][ch] = *reinterpret_cast<const short8*>(Wh1lo + off);
    }
  }
  float bias1[4];
  if (!isL0) {
    int cb = (tid & 3) * 4;
#pragma unroll
    for (int c = 0; c < 4; ++c) bias1[c] = bh1[n0 + cb + c];
  }

  for (int i = 0; i <= 128; ++i) {
    const bool active = isL0 ? (i < 128) : (i >= 1);
    if (active) {
      if (isL0) {
        const unsigned short* ah = H0hi + (size_t)i * 65536;
        const unsigned short* al = H0lo + (size_t)i * 65536;
        f32x4 acc[4][2] = {};
#pragma unroll
        for (int ch = 0; ch < 8; ++ch) {
          short8 Ah[4], Al[4];
#pragma unroll
          for (int rf = 0; rf < 4; ++rf) {
            size_t off = (size_t)(rf * 16 + fr) * 1024 + kw * 256 + ch * 32 + fk;
            Ah[rf] = *reinterpret_cast<const short8*>(ah + off);
            Al[rf] = *reinterpret_cast<const short8*>(al + off);
          }
#pragma unroll
          for (int rf = 0; rf < 4; ++rf)
#pragma unroll
            for (int cf = 0; cf < 2; ++cf) {
              acc[rf][cf] = MFMA(Ah[rf], bh_[cf][ch], acc[rf][cf]);
              acc[rf][cf] = MFMA(Al[rf], bh_[cf][ch], acc[rf][cf]);
              acc[rf][cf] = MFMA(Ah[rf], bl_[cf][ch], acc[rf][cf]);
            }
        }
#pragma unroll
        for (int rf = 0; rf < 4; ++rf)
#pragma unroll
          for (int cf = 0; cf < 2; ++cf)
#pragma unroll
            for (int r = 0; r < 4; ++r)
              red[kw][rf * 16 + pr + r][cf * 16 + fr] = acc[rf][cf][r];
      } else {
        const unsigned short* a0h = H0hi + (size_t)i * 65536;
        const unsigned short* a0l = H0lo + (size_t)i * 65536;
        const unsigned short* a1h = H1hi + (size_t)(i - 1) * 65536;
        const unsigned short* a1l = H1lo + (size_t)(i - 1) * 65536;
        f32x4 acc0[4] = {}, acc1[4] = {};
#pragma unroll
        for (int ch = 0; ch < 8; ++ch) {
          short8 A0h[4], A0l[4], A1h[4], A1l[4];
#pragma unroll
          for (int rf = 0; rf < 4; ++rf) {
            size_t off = (size_t)(rf * 16 + fr) * 1024 + kw * 256 + ch * 32 + fk;
            A0h[rf] = *reinterpret_cast<const short8*>(a0h + off);
            A0l[rf] = *reinterpret_cast<const short8*>(a0l + off);
            A1h[rf] = *reinterpret_cast<const short8*>(a1h + off);
            A1l[rf] = *reinterpret_cast<const short8*>(a1l + off);
          }
#pragma unroll
          for (int rf = 0; rf < 4; ++rf) {
            acc0[rf] = MFMA(A0h[rf], bh_[0][ch], acc0[rf]);
            acc0[rf] = MFMA(A0l[rf], bh_[0][ch], acc0[rf]);
            acc0[rf] = MFMA(A0h[rf], bl_[0][ch], acc0[rf]);
            acc1[rf] = MFMA(A1h[rf], bh_[1][ch], acc1[rf]);
            acc1[rf] = MFMA(A1l[rf], bh_[1][ch], acc1[rf]);
            acc1[rf] = MFMA(A1h[rf], bl_[1][ch], acc1[rf]);
          }
        }
#pragma unroll
        for (int rf = 0; rf < 4; ++rf)
#pragma unroll
          for (int r = 0; r < 4; ++r)
            red[kw][rf * 16 + pr + r][fr] = acc0[rf][r] + acc1[rf][r];
      }
      __syncthreads();
      if (isL0) {
        int row = tid >> 2, cb = (tid & 3) * 8;
        const float* Xt = X0 + (size_t)i * 65536 + (size_t)row * 1024 + n0;
        size_t ob = (size_t)(i + 1) * 65536 + (size_t)row * 1024 + n0;
#pragma unroll
        for (int c = 0; c < 8; ++c) {
          int col = cb + c;
          float s = red[0][row][col] + red[1][row][col] + red[2][row][col] + red[3][row][col];
          float val = tanhf(Xt[col] + s);
          unsigned short hb = f32_to_bf16_rn(val);
          float rem = val - bf16_to_f32(hb);
          __hip_atomic_store(H0hi + ob + col, hb, __ATOMIC_RELAXED, __HIP_MEMORY_SCOPE_AGENT);
          __hip_atomic_store(H0lo + ob + col, f32_to_bf16_rn(rem), __ATOMIC_RELAXED,
                             __HIP_MEMORY_SCOPE_AGENT);
        }
      } else {
        int row = tid >> 2, cb = (tid & 3) * 4;
        size_t ob = (size_t)i * 65536 + (size_t)row * 1024 + n0;
#pragma unroll
        for (int c = 0; c < 4; ++c) {
          int col = cb + c;
          float s = red[0][row][col] + red[1][row][col] + red[2][row][col] + red[3][row][col];
          float val = tanhf(bias1[c] + s);
          unsigned short hb = f32_to_bf16_rn(val);
          float rem = val - bf16_to_f32(hb);
          __hip_atomic_store(H1hi + ob + col, hb, __ATOMIC_RELAXED, __HIP_MEMORY_SCOPE_AGENT);
          __hip_atomic_store(H1lo + ob + col, f32_to_bf16_rn(rem), __ATOMIC_RELAXED,
                             __HIP_MEMORY_SCOPE_AGENT);
        }
      }
    }
    __syncthreads();  // drains all waves' stores (vmcnt 0) + protects LDS
    if (tid == 0) {
      __hip_atomic_store(&slots[wg * 32], (unsigned)(i + 1), __ATOMIC_RELAXED,
                         __HIP_MEMORY_SCOPE_AGENT);
      for (unsigned sp = 0; sp < SPIN_CAP; ++sp) {
        if (__hip_atomic_load(release, __ATOMIC_RELAXED, __HIP_MEMORY_SCOPE_AGENT) >=
            (unsigned)(i + 1))
          break;
        __builtin_amdgcn_s_sleep(1);
      }
    }
    __syncthreads();
  }
}

// ---------------- final hidden state: reconstruct f32 = hi + lo ----------------
__global__ void k_hidfinal(const unsigned short* __restrict__ H0hi,
                           const unsigned short* __restrict__ H0lo,
                           const unsigned short* __restrict__ H1hi,
                           const unsigned short* __restrict__ H1lo,
                           float* __restrict__ out) {
  size_t i = (size_t)blockIdx.x * 256 + threadIdx.x;  // 0..65535
  const size_t off = (size_t)128 * 65536;
  out[i] = bf16_to_f32(H0hi[off + i]) + bf16_to_f32(H0lo[off + i]);
  out[65536 + i] = bf16_to_f32(H1hi[off + i]) + bf16_to_f32(H1lo[off + i]);
}

// ---------------- launch ----------------
extern "C" void kernel_launch(void* const* d_in, const int* in_sizes, int n_in,
                              void* d_out, int out_size, void* d_ws, size_t ws_size,
                              hipStream_t stream) {
  const int* inputs = (const int*)d_in[0];
  const float* hidden = (const float*)d_in[1];
  const float* emb = (const float*)d_in[2];
  const float* wx0 = (const float*)d_in[3];
  const float* wh0 = (const float*)d_in[4];
  const float* bh0 = (const float*)d_in[5];
  const float* wx1 = (const float*)d_in[6];
  const float* wh1 = (const float*)d_in[7];
  const float* bh1 = (const float*)d_in[8];
  const float* v_w = (const float*)d_in[9];
  const float* v_b = (const float*)d_in[10];
  float* out = (float*)d_out;

  char* ws = (char*)d_ws;
  size_t off = 0;
  auto alloc = [&](size_t bytes) -> char* {
    char* p = ws + off;
    off += (bytes + 255) & ~(size_t)255;
    return p;
  };
  const size_t WB = (size_t)1024 * 1024 * 2;
  unsigned short* wx0hi = (unsigned short*)alloc(WB);
  unsigned short* wx0lo = (unsigned short*)alloc(WB);
  unsigned short* wh0hi = (unsigned short*)alloc(WB);
  unsigned short* wh0lo = (unsigned short*)alloc(WB);
  unsigned short* wx1hi = (unsigned short*)alloc(WB);
  unsigned short* wx1lo = (unsigned short*)alloc(WB);
  unsigned short* wh1hi = (unsigned short*)alloc(WB);
  unsigned short* wh1lo = (unsigned short*)alloc(WB);
  unsigned short* vwhi = (unsigned short*)alloc((size_t)10000 * 1024 * 2);
  unsigned short* vwlo = (unsigned short*)alloc((size_t)10000 * 1024 * 2);
  unsigned short* aehi = (unsigned short*)alloc((size_t)8192 * 1024 * 2);
  unsigned short* aelo = (unsigned short*)alloc((size_t)8192 * 1024 * 2);
  float* X0 = (float*)alloc((size_t)8192 * 1024 * 4);
  const size_t HS = (size_t)129 * 65536 * 2;
  unsigned short* H0hi = (unsigned short*)alloc(HS);
  unsigned short* H0lo = (unsigned short*)alloc(HS);
  unsigned short* H1hi = (unsigned short*)alloc(HS);
  unsigned short* H1lo = (unsigned short*)alloc(HS);
  unsigned* barbuf = (unsigned*)alloc(16384);  // slots (97*128B) + release
  unsigned* slots = barbuf;
  unsigned* release = barbuf + 100 * 32;

  k_split<<<1024, 256, 0, stream>>>(wx0, wx0hi, wx0lo, 1024 * 1024);
  k_split<<<1024, 256, 0, stream>>>(wh0, wh0hi, wh0lo, 1024 * 1024);
  k_split<<<1024, 256, 0, stream>>>(wx1, wx1hi, wx1lo, 1024 * 1024);
  k_split<<<1024, 256, 0, stream>>>(wh1, wh1hi, wh1lo, 1024 * 1024);
  k_split<<<10000, 256, 0, stream>>>(v_w, vwhi, vwlo, 10000 * 1024);
  k_split<<<64, 256, 0, stream>>>(hidden, H0hi, H0lo, 65536);
  k_split<<<64, 256, 0, stream>>>(hidden + 65536, H1hi, H1lo, 65536);
  k_embed<<<8192, 256, 0, stream>>>(inputs, emb, aehi, aelo);
  hipMemsetAsync(barbuf, 0, 16384, stream);

  dim3 g1(8, 64);
  k_gemm_nt<false><<<g1, 256, 0, stream>>>(aehi, aelo, wx0hi, wx0lo, X0, bh0, 1024);

  k_rnn_fused<<<97, 256, 0, stream>>>(X0, H0hi, H0lo, H1hi, H1lo, wh0hi, wh0lo, wx1hi, wx1lo,
                                      wh1hi, wh1lo, bh1, slots, release);

  dim3 g3(79, 64);
  k_gemm_nt<true><<<g3, 256, 0, stream>>>(H1hi + 65536, H1lo + 65536, vwhi, vwlo, out, v_b, 10000);
  k_hidfinal<<<256, 256, 0, stream>>>(H0hi, H0lo, H1hi, H1lo, out + (size_t)81920000);
}

// Round 6
// 3273.079 us; speedup vs baseline: 1.9947x; 1.1317x over previous
//
#include <hip/hip_runtime.h>
#include <stdint.h>

typedef __attribute__((ext_vector_type(8))) short short8;
typedef __attribute__((ext_vector_type(4))) float f32x4;
typedef __attribute__((ext_vector_type(4))) unsigned short ushort4v;
typedef __attribute__((ext_vector_type(4))) float float4v;
typedef __attribute__((ext_vector_type(2))) float float2v;

#define DEVFN static __device__ __forceinline__
#define SPIN_CAP (1u << 20)  // failsafe: wrong-results > wedged-container

DEVFN unsigned short f32_to_bf16_rn(float x) {
  unsigned u = __builtin_bit_cast(unsigned, x);
  unsigned r = u + 0x7FFFu + ((u >> 16) & 1u);
  return (unsigned short)(r >> 16);
}
DEVFN float bf16_to_f32(unsigned short h) {
  unsigned u = ((unsigned)h) << 16;
  return __builtin_bit_cast(float, u);
}
// opaque pin: forbids rematerialization of a loaded fragment (forces VGPR residency)
DEVFN void pin(short8& x) { asm volatile("" : "+v"(*reinterpret_cast<f32x4*>(&x))); }

// ---------------- split f32 -> (hi,lo) bf16 ----------------
__global__ void k_split(const float* __restrict__ src, unsigned short* __restrict__ hi,
                        unsigned short* __restrict__ lo, int n) {
  int i = (blockIdx.x * 256 + threadIdx.x) * 4;
  if (i >= n) return;
  float4v v = *reinterpret_cast<const float4v*>(src + i);
  ushort4v h, l;
#pragma unroll
  for (int j = 0; j < 4; ++j) {
    unsigned short hb = f32_to_bf16_rn(v[j]);
    float rem = v[j] - bf16_to_f32(hb);
    h[j] = hb;
    l[j] = f32_to_bf16_rn(rem);
  }
  *reinterpret_cast<ushort4v*>(hi + i) = h;
  *reinterpret_cast<ushort4v*>(lo + i) = l;
}

// ---------------- embedding gather + split ----------------
__global__ void k_embed(const int* __restrict__ tok, const float* __restrict__ emb,
                        unsigned short* __restrict__ hi, unsigned short* __restrict__ lo) {
  int m = blockIdx.x;  // 0..8191  (s*64+b)
  int t = tok[m];
  const float* row = emb + (size_t)t * 1024;
  int e = threadIdx.x * 4;
  float4v v = *reinterpret_cast<const float4v*>(row + e);
  ushort4v h, l;
#pragma unroll
  for (int j = 0; j < 4; ++j) {
    unsigned short hb = f32_to_bf16_rn(v[j]);
    float rem = v[j] - bf16_to_f32(hb);
    h[j] = hb;
    l[j] = f32_to_bf16_rn(rem);
  }
  *reinterpret_cast<ushort4v*>(hi + (size_t)m * 1024 + e) = h;
  *reinterpret_cast<ushort4v*>(lo + (size_t)m * 1024 + e) = l;
}

// ---------------- NT GEMM, 3-term bf16 split, C = A@B.T + bias ----------------
template <bool NGUARD>
__global__ __launch_bounds__(256) void k_gemm_nt(
    const unsigned short* __restrict__ Ahi, const unsigned short* __restrict__ Alo,
    const unsigned short* __restrict__ Bhi, const unsigned short* __restrict__ Blo,
    float* __restrict__ C, const float* __restrict__ bias, int N) {
  const int K = 1024;
  __shared__ unsigned short sA[2][128][40];
  __shared__ unsigned short sB[2][128][40];
  const int m0 = blockIdx.y * 128;
  const int n0 = blockIdx.x * 128;
  const int tid = threadIdx.x;
  const int lane = tid & 63, wave = tid >> 6;
  const int wm = (wave >> 1) * 64, wn = (wave & 1) * 64;
  const int fr = lane & 15, fk = (lane >> 4) * 8, fm = (lane >> 4) * 4;

  f32x4 acc[4][4] = {};

  for (int k0 = 0; k0 < K; k0 += 32) {
    __syncthreads();
#pragma unroll
    for (int a = 0; a < 2; ++a) {
      const unsigned short* As = a ? Alo : Ahi;
      const unsigned short* Bs = a ? Blo : Bhi;
#pragma unroll
      for (int p = 0; p < 2; ++p) {
        int seg = p * 256 + tid;
        int row = seg >> 2, sk = (seg & 3) * 8;
        short8 va = *reinterpret_cast<const short8*>(As + (size_t)(m0 + row) * K + k0 + sk);
        *reinterpret_cast<short8*>(&sA[a][row][sk]) = va;
        short8 vb;
        if (!NGUARD || (n0 + row) < N)
          vb = *reinterpret_cast<const short8*>(Bs + (size_t)(n0 + row) * K + k0 + sk);
        else
          vb = short8{0, 0, 0, 0, 0, 0, 0, 0};
        *reinterpret_cast<short8*>(&sB[a][row][sk]) = vb;
      }
    }
    __syncthreads();

    short8 afh[4], afl[4], bfh[4], bfl[4];
#pragma unroll
    for (int i = 0; i < 4; ++i) {
      afh[i] = *reinterpret_cast<const short8*>(&sA[0][wm + i * 16 + fr][fk]);
      afl[i] = *reinterpret_cast<const short8*>(&sA[1][wm + i * 16 + fr][fk]);
      bfh[i] = *reinterpret_cast<const short8*>(&sB[0][wn + i * 16 + fr][fk]);
      bfl[i] = *reinterpret_cast<const short8*>(&sB[1][wn + i * 16 + fr][fk]);
    }
#pragma unroll
    for (int i = 0; i < 4; ++i)
#pragma unroll
      for (int j = 0; j < 4; ++j) {
        acc[i][j] = __builtin_amdgcn_mfma_f32_16x16x32_bf16(afh[i], bfh[j], acc[i][j], 0, 0, 0);
        acc[i][j] = __builtin_amdgcn_mfma_f32_16x16x32_bf16(afl[i], bfh[j], acc[i][j], 0, 0, 0);
        acc[i][j] = __builtin_amdgcn_mfma_f32_16x16x32_bf16(afh[i], bfl[j], acc[i][j], 0, 0, 0);
      }
  }

#pragma unroll
  for (int i = 0; i < 4; ++i)
#pragma unroll
    for (int j = 0; j < 4; ++j) {
      int n = n0 + wn + j * 16 + fr;
      if (NGUARD && n >= N) continue;
      float bv = bias[n];
#pragma unroll
      for (int r = 0; r < 4; ++r) {
        int m = m0 + wm + i * 16 + fm + r;
        C[(size_t)m * N + n] = acc[i][j][r] + bv;
      }
    }
}

// ---------------- fused 2-layer recurrence, persistent ----------------
// Grid: 129 WGs x 512 thr (8 waves). WG 0..63: layer-0 (16 cols each).
// WG 64..127: layer-1 (16 cols, wx1+wh1 folded). WG 128: barrier checker.
// Interval i (0..128): L0 computes h0[i+1] (i<128); L1 computes h1[i] (i>=1).
// 8-way k-split (128 k/wave); weights PINNED in VGPRs via opaque asm.
// Barrier: per-WG slot store -> checker wave polls 128 slots -> 8 replicated
// release lines (workers poll replica wg&7, s_sleep backoff).
// All spins bounded (SPIN_CAP): sync bug => wrong data + counters, not a hang.
#define NWG_L0 64
#define WG_CHK 128

DEVFN f32x4 MFMA(short8 a, short8 b, f32x4 c) {
  return __builtin_amdgcn_mfma_f32_16x16x32_bf16(a, b, c, 0, 0, 0);
}

__global__ __launch_bounds__(512, 2) void k_rnn_fused(
    const float* __restrict__ X0,
    unsigned short* __restrict__ H0hi, unsigned short* __restrict__ H0lo,
    unsigned short* __restrict__ H1hi, unsigned short* __restrict__ H1lo,
    const unsigned short* __restrict__ Wh0hi, const unsigned short* __restrict__ Wh0lo,
    const unsigned short* __restrict__ Wx1hi, const unsigned short* __restrict__ Wx1lo,
    const unsigned short* __restrict__ Wh1hi, const unsigned short* __restrict__ Wh1lo,
    const float* __restrict__ bh1,
    unsigned* __restrict__ slots, unsigned* __restrict__ releases) {
  const int wg = blockIdx.x;
  const int tid = threadIdx.x;

  if (wg == WG_CHK) {  // ---- checker: one wave polls all 128 slots ----
    if (tid >= 64) return;
    const int lane = tid;
    for (int i = 0; i < 129; ++i) {
      unsigned want = (unsigned)(i + 1);
      for (unsigned sp = 0; sp < SPIN_CAP; ++sp) {
        unsigned a = __hip_atomic_load(&slots[lane * 32], __ATOMIC_RELAXED,
                                       __HIP_MEMORY_SCOPE_AGENT);
        unsigned b = __hip_atomic_load(&slots[(64 + lane) * 32], __ATOMIC_RELAXED,
                                       __HIP_MEMORY_SCOPE_AGENT);
        if (__all(a >= want && b >= want)) break;
        __builtin_amdgcn_s_sleep(2);
      }
      if (lane < 8)
        __hip_atomic_store(&releases[lane * 32], want, __ATOMIC_RELAXED,
                           __HIP_MEMORY_SCOPE_AGENT);
    }
    return;
  }

  const int lane = tid & 63, kw = tid >> 6;  // kw 0..7: k-slice owner (128 wide)
  const int fr = lane & 15, fk = (lane >> 4) * 8;
  const int pr = (lane >> 4) * 4;
  const bool isL0 = wg < NWG_L0;
  const int n0 = (isL0 ? wg : (wg - NWG_L0)) * 16;
  __shared__ float red[8][64][20];

  // ---- one-time weight load into registers, pinned for all 129 steps ----
  short8 w0h[4], w0l[4], w1h[4], w1l[4];
  if (isL0) {
#pragma unroll
    for (int ch = 0; ch < 4; ++ch) {
      size_t off = (size_t)(n0 + fr) * 1024 + kw * 128 + ch * 32 + fk;
      w0h[ch] = *reinterpret_cast<const short8*>(Wh0hi + off);
      w0l[ch] = *reinterpret_cast<const short8*>(Wh0lo + off);
      pin(w0h[ch]); pin(w0l[ch]);
    }
  } else {
#pragma unroll
    for (int ch = 0; ch < 4; ++ch) {
      size_t off = (size_t)(n0 + fr) * 1024 + kw * 128 + ch * 32 + fk;
      w0h[ch] = *reinterpret_cast<const short8*>(Wx1hi + off);
      w0l[ch] = *reinterpret_cast<const short8*>(Wx1lo + off);
      w1h[ch] = *reinterpret_cast<const short8*>(Wh1hi + off);
      w1l[ch] = *reinterpret_cast<const short8*>(Wh1lo + off);
      pin(w0h[ch]); pin(w0l[ch]); pin(w1h[ch]); pin(w1l[ch]);
    }
  }
  // combine-phase constants: thread covers (row, cols c0..c0+1)
  const int row = tid >> 3;
  const int c0 = (tid & 7) * 2;
  float bias0 = 0.f, bias1v = 0.f;
  if (!isL0) {
    bias0 = bh1[n0 + c0];
    bias1v = bh1[n0 + c0 + 1];
  }

  for (int i = 0; i <= 128; ++i) {
    const bool active = isL0 ? (i < 128) : (i >= 1);
    if (active) {
      if (isL0) {
        const unsigned short* ah = H0hi + (size_t)i * 65536 + kw * 128 + fk;
        const unsigned short* al = H0lo + (size_t)i * 65536 + kw * 128 + fk;
        f32x4 acc[4] = {};
#pragma unroll
        for (int ch = 0; ch < 4; ++ch) {
          short8 Ah[4], Al[4];
#pragma unroll
          for (int rf = 0; rf < 4; ++rf) {
            size_t off = (size_t)(rf * 16 + fr) * 1024 + ch * 32;
            Ah[rf] = *reinterpret_cast<const short8*>(ah + off);
            Al[rf] = *reinterpret_cast<const short8*>(al + off);
          }
#pragma unroll
          for (int rf = 0; rf < 4; ++rf) {
            acc[rf] = MFMA(Ah[rf], w0h[ch], acc[rf]);
            acc[rf] = MFMA(Al[rf], w0h[ch], acc[rf]);
            acc[rf] = MFMA(Ah[rf], w0l[ch], acc[rf]);
          }
        }
#pragma unroll
        for (int rf = 0; rf < 4; ++rf)
#pragma unroll
          for (int r = 0; r < 4; ++r) red[kw][rf * 16 + pr + r][fr] = acc[rf][r];
      } else {
        const unsigned short* a0h = H0hi + (size_t)i * 65536 + kw * 128 + fk;
        const unsigned short* a0l = H0lo + (size_t)i * 65536 + kw * 128 + fk;
        const unsigned short* a1h = H1hi + (size_t)(i - 1) * 65536 + kw * 128 + fk;
        const unsigned short* a1l = H1lo + (size_t)(i - 1) * 65536 + kw * 128 + fk;
        f32x4 acc0[4] = {}, acc1[4] = {};
#pragma unroll
        for (int ch = 0; ch < 4; ++ch) {
          short8 A0h[4], A0l[4], A1h[4], A1l[4];
#pragma unroll
          for (int rf = 0; rf < 4; ++rf) {
            size_t off = (size_t)(rf * 16 + fr) * 1024 + ch * 32;
            A0h[rf] = *reinterpret_cast<const short8*>(a0h + off);
            A0l[rf] = *reinterpret_cast<const short8*>(a0l + off);
            A1h[rf] = *reinterpret_cast<const short8*>(a1h + off);
            A1l[rf] = *reinterpret_cast<const short8*>(a1l + off);
          }
#pragma unroll
          for (int rf = 0; rf < 4; ++rf) {
            acc0[rf] = MFMA(A0h[rf], w0h[ch], acc0[rf]);
            acc0[rf] = MFMA(A0l[rf], w0h[ch], acc0[rf]);
            acc0[rf] = MFMA(A0h[rf], w0l[ch], acc0[rf]);
            acc1[rf] = MFMA(A1h[rf], w1h[ch], acc1[rf]);
            acc1[rf] = MFMA(A1l[rf], w1h[ch], acc1[rf]);
            acc1[rf] = MFMA(A1h[rf], w1l[ch], acc1[rf]);
          }
        }
#pragma unroll
        for (int rf = 0; rf < 4; ++rf)
#pragma unroll
          for (int r = 0; r < 4; ++r)
            red[kw][rf * 16 + pr + r][fr] = acc0[rf][r] + acc1[rf][r];
      }
      __syncthreads();
      // ---- combine 8 k-slices, activate, pack 2 bf16 -> one 4B store ----
      float s0 = 0.f, s1 = 0.f;
#pragma unroll
      for (int k8 = 0; k8 < 8; ++k8) {
        s0 += red[k8][row][c0];
        s1 += red[k8][row][c0 + 1];
      }
      float v0, v1;
      size_t ob;
      if (isL0) {
        const float* Xt = X0 + (size_t)i * 65536 + (size_t)row * 1024 + n0 + c0;
        v0 = tanhf(Xt[0] + s0);
        v1 = tanhf(Xt[1] + s1);
        ob = (size_t)(i + 1) * 65536 + (size_t)row * 1024 + n0 + c0;
      } else {
        v0 = tanhf(bias0 + s0);
        v1 = tanhf(bias1v + s1);
        ob = (size_t)i * 65536 + (size_t)row * 1024 + n0 + c0;
      }
      unsigned short hb0 = f32_to_bf16_rn(v0), hb1 = f32_to_bf16_rn(v1);
      unsigned short lb0 = f32_to_bf16_rn(v0 - bf16_to_f32(hb0));
      unsigned short lb1 = f32_to_bf16_rn(v1 - bf16_to_f32(hb1));
      unsigned uhi = (unsigned)hb0 | ((unsigned)hb1 << 16);
      unsigned ulo = (unsigned)lb0 | ((unsigned)lb1 << 16);
      unsigned short* dh = isL0 ? H0hi : H1hi;
      unsigned short* dl = isL0 ? H0lo : H1lo;
      __hip_atomic_store(reinterpret_cast<unsigned*>(dh + ob), uhi, __ATOMIC_RELAXED,
                         __HIP_MEMORY_SCOPE_AGENT);
      __hip_atomic_store(reinterpret_cast<unsigned*>(dl + ob), ulo, __ATOMIC_RELAXED,
                         __HIP_MEMORY_SCOPE_AGENT);
    }
    __syncthreads();  // drains all waves' stores (vmcnt 0) + protects LDS
    if (tid == 0) {
      __hip_atomic_store(&slots[wg * 32], (unsigned)(i + 1), __ATOMIC_RELAXED,
                         __HIP_MEMORY_SCOPE_AGENT);
      unsigned* myrel = &releases[(wg & 7) * 32];
      for (unsigned sp = 0; sp < SPIN_CAP; ++sp) {
        if (__hip_atomic_load(myrel, __ATOMIC_RELAXED, __HIP_MEMORY_SCOPE_AGENT) >=
            (unsigned)(i + 1))
          break;
        __builtin_amdgcn_s_sleep(4);
      }
    }
    __syncthreads();
  }
}

// ---------------- final hidden state: reconstruct f32 = hi + lo ----------------
__global__ void k_hidfinal(const unsigned short* __restrict__ H0hi,
                           const unsigned short* __restrict__ H0lo,
                           const unsigned short* __restrict__ H1hi,
                           const unsigned short* __restrict__ H1lo,
                           float* __restrict__ out) {
  size_t i = (size_t)blockIdx.x * 256 + threadIdx.x;  // 0..65535
  const size_t off = (size_t)128 * 65536;
  out[i] = bf16_to_f32(H0hi[off + i]) + bf16_to_f32(H0lo[off + i]);
  out[65536 + i] = bf16_to_f32(H1hi[off + i]) + bf16_to_f32(H1lo[off + i]);
}

// ---------------- launch ----------------
extern "C" void kernel_launch(void* const* d_in, const int* in_sizes, int n_in,
                              void* d_out, int out_size, void* d_ws, size_t ws_size,
                              hipStream_t stream) {
  const int* inputs = (const int*)d_in[0];
  const float* hidden = (const float*)d_in[1];
  const float* emb = (const float*)d_in[2];
  const float* wx0 = (const float*)d_in[3];
  const float* wh0 = (const float*)d_in[4];
  const float* bh0 = (const float*)d_in[5];
  const float* wx1 = (const float*)d_in[6];
  const float* wh1 = (const float*)d_in[7];
  const float* bh1 = (const float*)d_in[8];
  const float* v_w = (const float*)d_in[9];
  const float* v_b = (const float*)d_in[10];
  float* out = (float*)d_out;

  char* ws = (char*)d_ws;
  size_t off = 0;
  auto alloc = [&](size_t bytes) -> char* {
    char* p = ws + off;
    off += (bytes + 255) & ~(size_t)255;
    return p;
  };
  const size_t WB = (size_t)1024 * 1024 * 2;
  unsigned short* wx0hi = (unsigned short*)alloc(WB);
  unsigned short* wx0lo = (unsigned short*)alloc(WB);
  unsigned short* wh0hi = (unsigned short*)alloc(WB);
  unsigned short* wh0lo = (unsigned short*)alloc(WB);
  unsigned short* wx1hi = (unsigned short*)alloc(WB);
  unsigned short* wx1lo = (unsigned short*)alloc(WB);
  unsigned short* wh1hi = (unsigned short*)alloc(WB);
  unsigned short* wh1lo = (unsigned short*)alloc(WB);
  unsigned short* vwhi = (unsigned short*)alloc((size_t)10000 * 1024 * 2);
  unsigned short* vwlo = (unsigned short*)alloc((size_t)10000 * 1024 * 2);
  unsigned short* aehi = (unsigned short*)alloc((size_t)8192 * 1024 * 2);
  unsigned short* aelo = (unsigned short*)alloc((size_t)8192 * 1024 * 2);
  float* X0 = (float*)alloc((size_t)8192 * 1024 * 4);
  const size_t HS = (size_t)129 * 65536 * 2;
  unsigned short* H0hi = (unsigned short*)alloc(HS);
  unsigned short* H0lo = (unsigned short*)alloc(HS);
  unsigned short* H1hi = (unsigned short*)alloc(HS);
  unsigned short* H1lo = (unsigned short*)alloc(HS);
  unsigned* barbuf = (unsigned*)alloc(32768);  // 128 slots (128B each) + 8 release replicas
  unsigned* slots = barbuf;
  unsigned* releases = barbuf + 4096;  // byte offset 16384

  k_split<<<1024, 256, 0, stream>>>(wx0, wx0hi, wx0lo, 1024 * 1024);
  k_split<<<1024, 256, 0, stream>>>(wh0, wh0hi, wh0lo, 1024 * 1024);
  k_split<<<1024, 256, 0, stream>>>(wx1, wx1hi, wx1lo, 1024 * 1024);
  k_split<<<1024, 256, 0, stream>>>(wh1, wh1hi, wh1lo, 1024 * 1024);
  k_split<<<10000, 256, 0, stream>>>(v_w, vwhi, vwlo, 10000 * 1024);
  k_split<<<64, 256, 0, stream>>>(hidden, H0hi, H0lo, 65536);
  k_split<<<64, 256, 0, stream>>>(hidden + 65536, H1hi, H1lo, 65536);
  k_embed<<<8192, 256, 0, stream>>>(inputs, emb, aehi, aelo);
  hipMemsetAsync(barbuf, 0, 32768, stream);

  dim3 g1(8, 64);
  k_gemm_nt<false><<<g1, 256, 0, stream>>>(aehi, aelo, wx0hi, wx0lo, X0, bh0, 1024);

  k_rnn_fused<<<129, 512, 0, stream>>>(X0, H0hi, H0lo, H1hi, H1lo, wh0hi, wh0lo, wx1hi, wx1lo,
                                       wh1hi, wh1lo, bh1, slots, releases);

  dim3 g3(79, 64);
  k_gemm_nt<true><<<g3, 256, 0, stream>>>(H1hi + 65536, H1lo + 65536, vwhi, vwlo, out, v_b, 10000);
  k_hidfinal<<<256, 256, 0, stream>>>(H0hi, H0lo, H1hi, H1lo, out + (size_t)81920000);
}